// Round 1
// baseline (46.348 us; speedup 1.0000x reference)
//
#include <hip/hip_runtime.h>

// KAN activation: out[b,c,h,w] = scale_base[c]*silu(x) + scale_sp[c]*spline_c(x) + bias[c]
// spline_c(x) = sum_k coef[c,k] * B_k(x), cubic B-splines on UNIFORM knots
// t_i = -2.2 + 0.4*i (i=0..11). For x in [t_j, t_{j+1}) (j=0..10), with local
// t = (x - t_j)/0.4, the spline is a cubic polynomial whose Horner coefficients
// are fixed linear combos of coef[c, j-3..j] (zero-padded outside [0,8)).
// We precompute those 11 float4 coefficient vectors per block (one channel per
// block) into LDS; slot 11 = zeros handles x outside [-2.2, 2.2).

constexpr int C_DIM   = 64;
constexpr int HW      = 128 * 128;   // elements per (b,c) plane
constexpr int NB      = 8;           // basis count
constexpr int THREADS = 256;
constexpr int VEC     = 4;
constexpr int ITERS   = HW / (THREADS * VEC);  // 16

__device__ __forceinline__ float kan_one(float xv, const float4* a_lds,
                                         float sb, float sp, float bi) {
    // silu(x) = x / (1 + exp(-x))
    float e    = __expf(-xv);
    float sig  = __builtin_amdgcn_rcpf(1.0f + e);
    float silu = xv * sig;

    // spline interval: u = (x + 2.2)/0.4 = 2.5x + 5.5
    float u  = fmaf(xv, 2.5f, 5.5f);
    float jf = floorf(u);
    float t  = u - jf;
    int   j  = (int)jf;
    bool valid = (u >= 0.0f) && (u < 11.0f);
    int   jj = valid ? j : 11;           // slot 11 is all-zero -> spline = 0
    float4 a = a_lds[jj];                // ds_read_b128
    float spl = fmaf(t, fmaf(t, fmaf(t, a.w, a.z), a.y), a.x);

    return fmaf(sb, silu, fmaf(sp, spl, bi));
}

__global__ __launch_bounds__(THREADS) void kan_kernel(
    const float* __restrict__ x,
    const float* __restrict__ coef,
    const float* __restrict__ scale_base,
    const float* __restrict__ scale_sp,
    const float* __restrict__ bias,
    float* __restrict__ out)
{
    __shared__ float4 a_lds[12];

    const int plane = blockIdx.x;        // b*C + c
    const int c     = plane & (C_DIM - 1);
    const int tid   = threadIdx.x;

    if (tid < 12) {
        float4 a = make_float4(0.0f, 0.0f, 0.0f, 0.0f);
        if (tid < 11) {
            // co[d] = coef[c, tid-3+d], zero-padded
            float co[4];
            #pragma unroll
            for (int d = 0; d < 4; ++d) {
                int idx = tid - 3 + d;
                co[d] = (idx >= 0 && idx < NB) ? coef[c * NB + idx] : 0.0f;
            }
            // uniform cubic B-spline -> Horner coefficients
            a.x = (co[0] + 4.0f * co[1] + co[2]) * (1.0f / 6.0f);
            a.y = (co[2] - co[0]) * 0.5f;
            a.z = (co[0] + co[2]) * 0.5f - co[1];
            a.w = (co[3] - co[0]) * (1.0f / 6.0f) + (co[1] - co[2]) * 0.5f;
        }
        a_lds[tid] = a;
    }
    const float sb = scale_base[c];
    const float sp = scale_sp[c];
    const float bi = bias[c];
    __syncthreads();

    const float4* __restrict__ xin  =
        reinterpret_cast<const float4*>(x) + (size_t)plane * (HW / VEC);
    float4* __restrict__ xout =
        reinterpret_cast<float4*>(out) + (size_t)plane * (HW / VEC);

    #pragma unroll 4
    for (int it = 0; it < ITERS; ++it) {
        const int vi = it * THREADS + tid;
        float4 v = xin[vi];
        float4 r;
        r.x = kan_one(v.x, a_lds, sb, sp, bi);
        r.y = kan_one(v.y, a_lds, sb, sp, bi);
        r.z = kan_one(v.z, a_lds, sb, sp, bi);
        r.w = kan_one(v.w, a_lds, sb, sp, bi);
        xout[vi] = r;
    }
}

extern "C" void kernel_launch(void* const* d_in, const int* in_sizes, int n_in,
                              void* d_out, int out_size, void* d_ws, size_t ws_size,
                              hipStream_t stream) {
    const float* x          = (const float*)d_in[0];
    const float* coef       = (const float*)d_in[1];
    const float* scale_base = (const float*)d_in[2];
    const float* scale_sp   = (const float*)d_in[3];
    const float* bias       = (const float*)d_in[4];
    float* out              = (float*)d_out;

    const int planes = in_sizes[0] / HW;   // B*C = 2048
    kan_kernel<<<planes, THREADS, 0, stream>>>(x, coef, scale_base, scale_sp, bias, out);
}